// Round 4
// baseline (93.216 us; speedup 1.0000x reference)
//
#include <hip/hip_runtime.h>

// Sequential 1001-step closed-loop double-integrator sim with teacher forcing
// and early stopping. Inherently serial (nonlinear v/p recurrence).
// R4: single-wave kernel, NO LDS, no barriers.
//   - all (u, w*u, tf) staged into per-lane VGPRs (16 regs/lane x 64 lanes)
//   - serial loop runs redundantly on all 64 lanes; per-step data via
//     v_readlane (VALU latency, no memory ops in the loop)
//   - carried wrp = w*rcp(p): f = fmaf(-wrp, v_in, wu); p-cycle = 16 cy
//   - rcp without Newton refine (1 ulp; threshold 16.96 has huge slack,
//     teacher forcing resets v-error every ~2 steps)
//   - stop check is 1 iteration stale (branch condition ready, no stall)

#define N_STEPS 1001
#define NV 16            // ceil(1001/64) VGPRs per staged array
#define DT_F 0.05f
#define LO_F 0.05f
#define HI_F 1000.0f

__device__ __forceinline__ float fast_rcp(float x) {
    return __builtin_amdgcn_rcpf(x);
}

#if __has_builtin(__builtin_amdgcn_readlane)
__device__ __forceinline__ float rl_f(float x, int i) {
    return __int_as_float(__builtin_amdgcn_readlane(__float_as_int(x), i));
}
#else
__device__ __forceinline__ float rl_f(float x, int i) { return __shfl(x, i, 64); }
#endif

__global__ __launch_bounds__(64) void sim_scan_kernel(
    const float* __restrict__ inputs,
    const float* __restrict__ fc1_w,
    const void* __restrict__ tf_mask,
    float* __restrict__ out)
{
    const int lane = threadIdx.x;   // one wave: 0..63

    // Zero the output (zeros required after the stop step; harness poisons
    // d_out with 0xAA before timing and does not re-poison).
    for (int i = lane; i < N_STEPS + 1; i += 64) out[i] = 0.0f;

    // --- tf_mask element-width detection, wave-parallel ---
    // int32 0/1: bytes at i%4!=0 are all zero. int64 0/1: additionally bytes
    // at i%8==4 are zero. 1-byte bool: ~300 random 0/1 bytes in 1..399 ->
    // some nonzero with prob 1 - 2^-300.
    const unsigned char* mb = (const unsigned char*)tf_mask;
    bool nm4 = false, m84 = false;
    for (int i = 1 + lane; i < 400; i += 64) {
        unsigned char b = mb[i];
        if (b) { if ((i & 3) != 0) nm4 = true; else if ((i & 7) == 4) m84 = true; }
    }
    const int width = __any(nm4) ? 1 : (__any(m84) ? 4 : 8);

    const float w = fc1_w[0];

    // --- stage (u, w*u, tf) into per-lane VGPRs: element k lives in
    // lane (k%64), register (k/64). Fully static indexing -> stays in VGPRs.
    float uv[NV], wuv[NV], tfv[NV];
#pragma unroll
    for (int j = 0; j < NV; ++j) {
        const int k = j * 64 + lane;
        float u = 0.0f; bool tf = false;
        if (k < N_STEPS) {
            u = inputs[k];
            if (width == 1)      tf = mb[k] != 0;
            else if (width == 4) tf = ((const int*)tf_mask)[k] != 0;
            else                 tf = ((const long long*)tf_mask)[k] != 0;
        }
        uv[j] = u; wuv[j] = w * u; tfv[j] = tf ? 1.0f : 0.0f;
    }

    const float c1 = DT_F * DT_F * 0.5f;   // dt^2/2

    // All 64 lanes run the serial scan redundantly (identical values, no
    // divergence). Stores hit the same address with the same value -> the
    // coalescer merges them into one transaction.
    float p = 100.0f, v = 0.0f;
    float r0 = fast_rcp(p);
    float wrp = w * (r0 * fmaf(-p, r0, 2.0f));  // refined once at init

    int kstop = -1;
    bool hitprev = false;

#pragma unroll
    for (int j = 0; j < NV; ++j) {
        if (kstop >= 0) break;
        const int kbase = j * 64;
        const int lim = (N_STEPS - kbase < 64) ? (N_STEPS - kbase) : 64;
        for (int i = 0; i < lim; ++i) {
            // stop check is one iteration stale: condition fully resolved,
            // no VALU->branch wait; nothing was stored for this step yet.
            if (hitprev) { kstop = kbase + i - 1; break; }

            const float u   = rl_f(uv[j],  i);
            const float wu  = rl_f(wuv[j], i);
            const float tfl = rl_f(tfv[j], i);

            const float pu   = p * u;
            const float v_in = (tfl != 0.0f) ? pu : v;   // teacher forcing

            // f = w*(u - v_in/p) via carried wrp = w/p
            const float f  = fmaf(-wrp, v_in, wu);
            const float t1 = fmaf(DT_F, v_in, p);
            const float pn = fmaf(c1, f, t1);            // p + DT*v_in + c1*f
            const float vn = fmaf(DT_F, f, v_in);        // v_in + DT*f

            const float r = fast_rcp(pn);                // feeds out AND next wrp
            out[kbase + i] = vn * r;                     // emitted on hit step too

            hitprev = (pn < LO_F) | (pn > HI_F);
            p = pn; v = vn; wrp = w * r;
        }
    }
    if (kstop < 0) kstop = N_STEPS - 1;   // covers hit-at-last-step and no-hit

    out[N_STEPS] = (float)kstop;  // k_stop as float (flat f32 output)
}

extern "C" void kernel_launch(void* const* d_in, const int* in_sizes, int n_in,
                              void* d_out, int out_size, void* d_ws, size_t ws_size,
                              hipStream_t stream) {
    const float* inputs = (const float*)d_in[0];
    const float* fc1_w  = (const float*)d_in[1];
    const void*  tfm    = d_in[2];
    (void)in_sizes; (void)n_in; (void)out_size; (void)d_ws; (void)ws_size;

    sim_scan_kernel<<<dim3(1), dim3(64), 0, stream>>>(
        inputs, fc1_w, tfm, (float*)d_out);
}

// Round 5
// 74.200 us; speedup vs baseline: 1.2563x; 1.2563x over previous
//
#include <hip/hip_runtime.h>

// Sequential 1001-step closed-loop double-integrator sim with teacher forcing
// and early stopping. Inherently serial (nonlinear v/p recurrence).
// R5: single wave, no LDS. Per-step data in VGPRs (readlane) + tf as SGPR
// bitmasks (ballot). Teacher-forced steps use the algebraic identity
// net_in = u - (p*u)/p ~= 0  =>  pn = fma(DT*u, p, p), vn = p*u  (no rcp).
// Non-tf steps use carried rp = rcp(pn_prev) (1 ulp, R4 precedent).
// Outer block loop fully unrolls (no break -> no scratch spill).

#define N_STEPS 1001
#define NB 16            // ceil(1001/64) 64-step blocks
#define DT_F 0.05f
#define LO_F 0.05f
#define HI_F 1000.0f

__device__ __forceinline__ float fast_rcp(float x) {
    return __builtin_amdgcn_rcpf(x);
}

#if __has_builtin(__builtin_amdgcn_readlane)
__device__ __forceinline__ float rl_f(float x, int i) {
    return __int_as_float(__builtin_amdgcn_readlane(__float_as_int(x), i));
}
#else
__device__ __forceinline__ float rl_f(float x, int i) { return __shfl(x, i, 64); }
#endif

__global__ __launch_bounds__(64) void sim_scan_kernel(
    const float* __restrict__ inputs,
    const float* __restrict__ fc1_w,
    const void* __restrict__ tf_mask,
    float* __restrict__ out)
{
    const int lane = threadIdx.x;   // one wave

    // --- tf_mask element-width detection, wave-parallel ---
    // int32 0/1: bytes at i%4!=0 all zero. int64 0/1: additionally i%8==4
    // zero. 1-byte bool: ~300 random 0/1 bytes in 1..399 -> nonzero with
    // prob 1 - 2^-300.
    const unsigned char* mb = (const unsigned char*)tf_mask;
    bool nm4 = false, m84 = false;
    for (int i = 1 + lane; i < 400; i += 64) {
        unsigned char b = mb[i];
        if (b) { if ((i & 3) != 0) nm4 = true; else if ((i & 7) == 4) m84 = true; }
    }
    const int width = __any(nm4) ? 1 : (__any(m84) ? 4 : 8);

    const float w   = fc1_w[0];
    const float c1w = (DT_F * DT_F * 0.5f) * w;   // 0.00125*w
    const float dw  = DT_F * w;

    // --- stage u, DT*u into per-lane VGPRs; tf into 16 wave bitmasks ---
    float uv[NB], duv[NB];
    unsigned long long mj[NB];
#pragma unroll
    for (int j = 0; j < NB; ++j) {
        const int k = j * 64 + lane;
        float u = 0.0f; bool tf = false;
        if (k < N_STEPS) {
            u = inputs[k];
            if (width == 1)      tf = mb[k] != 0;
            else if (width == 4) tf = ((const int*)tf_mask)[k] != 0;
            else                 tf = ((const long long*)tf_mask)[k] != 0;
        }
        uv[j] = u; duv[j] = DT_F * u;
        mj[j] = __ballot(tf);
    }

    // All 64 lanes run the scan redundantly (identical values, no divergence).
    float p = 100.0f, v = 0.0f;
    float rp = fast_rcp(100.0f);    // carried ~1/p (1 ulp)

    int  kstop   = N_STEPS - 1;     // default: also covers hit-at-last-step
    bool done    = false;
    bool hitprev = false;

#pragma unroll
    for (int j = 0; j < NB; ++j) {
        if (!done) {
            const unsigned long long m = mj[j];
            const int lim = (j == NB - 1) ? (N_STEPS - (NB - 1) * 64) : 64;
            for (int i = 0; i < lim; ++i) {
                // stale stop-check: condition fully resolved an iteration ago
                if (hitprev) { kstop = j * 64 + i - 1; done = true; break; }

                float pn, vn;
                if ((m >> i) & 1ull) {
                    // teacher forcing: net_in = u-(p*u)/p ~= 0 (err ~1e-10)
                    const float u  = rl_f(uv[j],  i);
                    const float du = rl_f(duv[j], i);
                    pn = fmaf(du, p, p);        // p*(1+DT*u)
                    vn = p * u;
                } else {
                    const float u = rl_f(uv[j], i);
                    const float t = fmaf(-v, rp, u);            // u - v/p
                    pn = fmaf(c1w, t, fmaf(DT_F, v, p));        // p+DT*v+c1*f
                    vn = fmaf(dw, t, v);                        // v+DT*f
                }
                const float rq = fast_rcp(pn);  // feeds out AND next step
                out[j * 64 + i] = vn * rq;      // emitted on the hit step too

                hitprev = (pn < LO_F) | (pn > HI_F);  // exact, matches ref
                p = pn; v = vn; rp = rq;
            }
        }
    }

    // tail zeros (k > kstop) and k_stop; wave-parallel, disjoint addresses
    for (int k2 = kstop + 1 + lane; k2 < N_STEPS; k2 += 64) out[k2] = 0.0f;
    out[N_STEPS] = (float)kstop;
}

extern "C" void kernel_launch(void* const* d_in, const int* in_sizes, int n_in,
                              void* d_out, int out_size, void* d_ws, size_t ws_size,
                              hipStream_t stream) {
    const float* inputs = (const float*)d_in[0];
    const float* fc1_w  = (const float*)d_in[1];
    const void*  tfm    = d_in[2];
    (void)in_sizes; (void)n_in; (void)out_size; (void)d_ws; (void)ws_size;

    sim_scan_kernel<<<dim3(1), dim3(64), 0, stream>>>(
        inputs, fc1_w, tfm, (float*)d_out);
}

// Round 7
// 39.745 us; speedup vs baseline: 2.3454x; 1.8669x over previous
//
#include <hip/hip_runtime.h>

// Sequential 1001-step closed-loop double-integrator sim with teacher forcing
// and early stopping. Inherently serial (nonlinear v/p recurrence).
// R7 (= R6 with the writelane builtin removed — it doesn't exist on gfx950's
// toolchain; replaced by a 2-op predicated select):
//   - single wave; fully-unrolled 64-step blocks, branchless per step
//   - NO compiler-managed arrays (R4/R5 spilled to scratch: VGPR=20 proved it)
//   - per block: u in ONE VGPR (global load), tf in ONE VGPR (LDS floats),
//     accessed via v_readlane with immediate index after unroll
//   - tf select via exact fma arithmetic (ts in {0,1}) -> no branches
//   - speculative stop: pn recorded into lane i of pblk via cmp+cndmask;
//     one ballot+ctz per block finds the first OOB step; tail-zero fixes
//     any garbage stores past the hit (after s_waitcnt vmcnt(0))
//   - t = u - o_prev (previous output IS v/p) -> rcp only feeds output

#define N_STEPS 1001
#define DT_F 0.05f
#define LO_F 0.05f
#define HI_F 1000.0f

__device__ __forceinline__ float fast_rcp(float x) {
    return __builtin_amdgcn_rcpf(x);
}
__device__ __forceinline__ float rl_f(float x, int i) {
    return __int_as_float(__builtin_amdgcn_readlane(__float_as_int(x), i));
}

// one simulation step; i is a compile-time-constant lane index after unroll
#define SIM_STEP(i, ob) do {                                     \
    const float u_  = rl_f(u_cur, (i));                          \
    const float ts_ = rl_f(f_cur, (i));   /* tf as 1.0/0.0 */    \
    const float tc_ = 1.0f - ts_;                                \
    const float pu_ = p * u_;                                    \
    const float tv_ = tc_ * v;                                   \
    const float vi_ = fmaf(ts_, pu_, tv_);  /* exact select */   \
    const float d_  = u_ - o;               /* u - v/p */        \
    const float t_  = tc_ * d_;             /* 0 when tf */      \
    const float pn_ = fmaf(c1w, t_, fmaf(DT_F, vi_, p));         \
    const float vn_ = fmaf(dw, t_, vi_);                         \
    const float rq_ = fast_rcp(pn_);                             \
    o = vn_ * rq_;                                               \
    (ob)[(i)] = o;                                               \
    pblk = (lane == (i)) ? pn_ : pblk;  /* record step's pn */   \
    p = pn_; v = vn_;                                            \
} while (0)

__global__ __launch_bounds__(64) void sim_scan_kernel(
    const float* __restrict__ inputs,
    const float* __restrict__ fc1_w,
    const void* __restrict__ tf_mask,
    float* __restrict__ out)
{
    __shared__ float s_tf[1024];
    const int lane = threadIdx.x;   // one wave

    // --- tf_mask element-width detection, wave-parallel ---
    // int32 0/1: bytes at i%4!=0 all zero. int64 0/1: additionally i%8==4
    // zero. 1-byte bool: ~300 random 0/1 bytes in 1..399 -> nonzero with
    // prob 1 - 2^-300.
    const unsigned char* mb = (const unsigned char*)tf_mask;
    bool nm4 = false, m84 = false;
    for (int i = 1 + lane; i < 400; i += 64) {
        unsigned char b = mb[i];
        if (b) { if ((i & 3) != 0) nm4 = true; else if ((i & 7) == 4) m84 = true; }
    }
    const int width = __any(nm4) ? 1 : (__any(m84) ? 4 : 8);

    // --- stage tf as floats into LDS (single wave: lgkmcnt orders ds ops) ---
    for (int j = 0; j < 16; ++j) {
        const int k = j * 64 + lane;
        bool tf = false;
        if (k < N_STEPS) {
            if (width == 1)      tf = mb[k] != 0;
            else if (width == 4) tf = ((const int*)tf_mask)[k] != 0;
            else                 tf = ((const long long*)tf_mask)[k] != 0;
        }
        s_tf[k] = tf ? 1.0f : 0.0f;
    }

    const float w   = fc1_w[0];
    const float c1w = (DT_F * DT_F * 0.5f) * w;   // 0.00125*w
    const float dw  = DT_F * w;                    // 0.05*w

    // All 64 lanes run the scan redundantly (identical values, no divergence).
    float p = 100.0f, v = 0.0f, o = 0.0f;  // o = v/p = 0 initially
    int  kstop = N_STEPS - 1;
    bool hit = false;

    float u_cur = inputs[lane];
    float f_cur = s_tf[lane];

    for (int j = 0; j < 15; ++j) {          // 15 full 64-step blocks
        // prefetch next block's data (hidden under this block's compute)
        const int kn = (j + 1) * 64 + lane;
        float u_nxt = 0.0f;
        if (kn < N_STEPS) u_nxt = inputs[kn];
        const float f_nxt = s_tf[kn];       // kn <= 1023, in bounds

        float pblk = 100.0f;                // in-range default
        float* ob = out + j * 64;
#pragma unroll
        for (int i = 0; i < 64; ++i) SIM_STEP(i, ob);

        // first OOB step in this block, if any (speculation fixed by ctz)
        const unsigned long long hm = __ballot((pblk < LO_F) || (pblk > HI_F));
        if (hm) { kstop = j * 64 + (__ffsll(hm) - 1); hit = true; break; }

        u_cur = u_nxt; f_cur = f_nxt;
    }

    if (!hit) {                              // tail block: 41 steps
        float pblk = 100.0f;
        float* ob = out + 960;
#pragma unroll
        for (int i = 0; i < 41; ++i) SIM_STEP(i, ob);
        const unsigned long long hm = __ballot((pblk < LO_F) || (pblk > HI_F));
        if (hm) kstop = 960 + (__ffsll(hm) - 1);
    }

    // drain speculative stores, then zero everything past the stop step
    asm volatile("s_waitcnt vmcnt(0)" ::: "memory");
    for (int k2 = kstop + 1 + lane; k2 < N_STEPS; k2 += 64) out[k2] = 0.0f;
    out[N_STEPS] = (float)kstop;   // k_stop as float (flat f32 output)
}

extern "C" void kernel_launch(void* const* d_in, const int* in_sizes, int n_in,
                              void* d_out, int out_size, void* d_ws, size_t ws_size,
                              hipStream_t stream) {
    const float* inputs = (const float*)d_in[0];
    const float* fc1_w  = (const float*)d_in[1];
    const void*  tfm    = d_in[2];
    (void)in_sizes; (void)n_in; (void)out_size; (void)d_ws; (void)ws_size;

    sim_scan_kernel<<<dim3(1), dim3(64), 0, stream>>>(
        inputs, fc1_w, tfm, (float*)d_out);
}